// Round 3
// baseline (1002.477 us; speedup 1.0000x reference)
//
#include <hip/hip_runtime.h>

typedef _Float16 f16;
typedef _Float16 f16x4 __attribute__((ext_vector_type(4)));
typedef _Float16 f16x8 __attribute__((ext_vector_type(8)));
typedef float    f32x4 __attribute__((ext_vector_type(4)));

#define MFMA16(a,b,c) __builtin_amdgcn_mfma_f32_16x16x32_f16((a),(b),(c),0,0,0)

#define LATENT 64
#define HIDDEN 128

// A-fragment of W[out][K] for out-tile `tile`, k-chunk kf (32 wide).
// mfma_f32_16x16x32_f16 A layout: row = lane%16, k = kf*32 + 8*(lane/16)+j
__device__ __forceinline__ f16x8 load_afrag(const float* __restrict__ W, int K,
                                            int tile, int kf, int lane) {
  const int row = tile * 16 + (lane & 15);
  const int k0  = kf * 32 + (lane >> 4) * 8;
  const float* p = W + row * K + k0;
  f16x8 r;
#pragma unroll
  for (int j = 0; j < 8; ++j) r[j] = (f16)p[j];
  return r;
}

// B-fragment from LDS activation tile [16 rows][dims] f16, XOR-swizzled rows.
__device__ __forceinline__ f16x8 bfrag(const f16* buf, int rowb, int k0, int lane) {
  const int b  = lane & 15;
  const int kk = k0 + (lane >> 4) * 8;
  const int off = b * rowb + ((kk * 2) ^ ((b & 7) << 4));
  return *(const f16x8*)((const char*)buf + off);
}

// Write one D-tile (f32x4 -> f16x4) into an activation buffer, same swizzle.
__device__ __forceinline__ void dwrite(f16* buf, int rowb, int dbase, f32x4 v, int lane) {
  const int b = lane & 15;
  f16x4 h;
#pragma unroll
  for (int i = 0; i < 4; ++i) h[i] = (f16)v[i];
  const int off = b * rowb + ((dbase * 2) ^ ((b & 7) << 4));
  *(f16x4*)((char*)buf + off) = h;
}

__device__ __forceinline__ f32x4 elu4(f32x4 d) {
#pragma unroll
  for (int i = 0; i < 4; ++i) {
    const float e = __expf(d[i]) - 1.f;
    d[i] = d[i] > 0.f ? d[i] : e;
  }
  return d;
}

// ============ kernel 1: RK4 integrator, 1 wave per 16-row tile, NO barriers ============
__global__ __launch_bounds__(64, 1)
void node_int(const float* __restrict__ z0,   const float* __restrict__ tg,
              const float* __restrict__ fc1w, const float* __restrict__ fc1b,
              const float* __restrict__ fc2w, const float* __restrict__ fc2b,
              const float* __restrict__ fc3w, const float* __restrict__ fc3b,
              float* __restrict__ out, int Btot, int T) {
  __shared__ __align__(16) f16 xb[16 * 64];    // f-input staging (wave-private)
  __shared__ __align__(16) f16 h1[16 * 128];
  __shared__ __align__(16) f16 h2[16 * 128];

  const int lane = threadIdx.x;   // 64 threads = 1 wave
  const int grp  = lane >> 4;
  const int bcol = lane & 15;
  const int row0 = blockIdx.x * 16;
  const f32x4 Z0 = {0.f, 0.f, 0.f, 0.f};

  // all f-weights in registers: 64 frags = 256 VGPR; biases 80 VGPR (C-in)
  f16x8 a1[8][2], a2[8][4], a3[4][4];
  f32x4 b1[8], b2[8], b3[4];
#pragma unroll
  for (int ot = 0; ot < 8; ++ot) {
    a1[ot][0] = load_afrag(fc1w, 64, ot, 0, lane);
    a1[ot][1] = load_afrag(fc1w, 64, ot, 1, lane);
#pragma unroll
    for (int kf = 0; kf < 4; ++kf) a2[ot][kf] = load_afrag(fc2w, 128, ot, kf, lane);
    b1[ot] = *(const f32x4*)(fc1b + ot * 16 + grp * 4);
    b2[ot] = *(const f32x4*)(fc2b + ot * 16 + grp * 4);
  }
#pragma unroll
  for (int ot = 0; ot < 4; ++ot) {
#pragma unroll
    for (int kf = 0; kf < 4; ++kf) a3[ot][kf] = load_afrag(fc3w, 128, ot, kf, lane);
    b3[ot] = *(const f32x4*)(fc3b + ot * 16 + grp * 4);
  }

  f32x4 z[4];
#pragma unroll
  for (int zt = 0; zt < 4; ++zt)
    z[zt] = *(const f32x4*)(z0 + (size_t)(row0 + bcol) * LATENT + zt * 16 + grp * 4);

  // f(x): stage x, 3 layers, no barriers (same-wave LDS, lgkmcnt only)
  auto feval = [&](const f32x4 x[4], f32x4 k[4]) {
#pragma unroll
    for (int zt = 0; zt < 4; ++zt) dwrite(xb, 128, zt * 16 + grp * 4, x[zt], lane);
    const f16x8 v0 = bfrag(xb, 128, 0, lane);
    const f16x8 v1 = bfrag(xb, 128, 32, lane);
#pragma unroll
    for (int ot = 0; ot < 8; ++ot) {
      f32x4 d = MFMA16(a1[ot][0], v0, b1[ot]);
      d = MFMA16(a1[ot][1], v1, d);
      d = elu4(d);
      dwrite(h1, 256, ot * 16 + grp * 4, d, lane);
    }
    f16x8 h[4];
#pragma unroll
    for (int kf = 0; kf < 4; ++kf) h[kf] = bfrag(h1, 256, kf * 32, lane);
#pragma unroll
    for (int ot = 0; ot < 8; ++ot) {
      f32x4 c0 = MFMA16(a2[ot][0], h[0], b2[ot]);
      c0 = MFMA16(a2[ot][1], h[1], c0);
      f32x4 c1 = MFMA16(a2[ot][2], h[2], Z0);
      c1 = MFMA16(a2[ot][3], h[3], c1);
      f32x4 d = elu4(c0 + c1);
      dwrite(h2, 256, ot * 16 + grp * 4, d, lane);
    }
    f16x8 g[4];
#pragma unroll
    for (int kf = 0; kf < 4; ++kf) g[kf] = bfrag(h2, 256, kf * 32, lane);
#pragma unroll
    for (int ot = 0; ot < 4; ++ot) {
      f32x4 c0 = MFMA16(a3[ot][0], g[0], b3[ot]);
      c0 = MFMA16(a3[ot][1], g[1], c0);
      f32x4 c1 = MFMA16(a3[ot][2], g[2], Z0);
      c1 = MFMA16(a3[ot][3], g[3], c1);
      k[ot] = c0 + c1;
    }
  };

  float t_cur = tg[0];
  float t_nxt = tg[1];
  for (int s = 0; s < T; ++s) {
    // publish z_s (raw latent) into d_out; kernel 2 decodes in place
#pragma unroll
    for (int zt = 0; zt < 4; ++zt)
      *(f32x4*)(out + ((size_t)s * Btot + row0 + bcol) * LATENT + zt * 16 + grp * 4) = z[zt];
    if (s == T - 1) break;

    const float t_fut = tg[s + 2 < T ? s + 2 : T - 1];  // prefetch next dt operand
    const float dt = t_nxt - t_cur;

    f32x4 k[4], acc[4], xs[4];
    feval(z, k);                       // k1
#pragma unroll
    for (int zt = 0; zt < 4; ++zt) {
      acc[zt] = k[zt];
#pragma unroll
      for (int i = 0; i < 4; ++i) xs[zt][i] = z[zt][i] + 0.5f * dt * k[zt][i];
    }
    feval(xs, k);                      // k2
#pragma unroll
    for (int zt = 0; zt < 4; ++zt)
#pragma unroll
      for (int i = 0; i < 4; ++i) {
        acc[zt][i] += 2.f * k[zt][i];
        xs[zt][i] = z[zt][i] + 0.5f * dt * k[zt][i];
      }
    feval(xs, k);                      // k3
#pragma unroll
    for (int zt = 0; zt < 4; ++zt)
#pragma unroll
      for (int i = 0; i < 4; ++i) {
        acc[zt][i] += 2.f * k[zt][i];
        xs[zt][i] = z[zt][i] + dt * k[zt][i];
      }
    feval(xs, k);                      // k4
#pragma unroll
    for (int zt = 0; zt < 4; ++zt)
#pragma unroll
      for (int i = 0; i < 4; ++i) z[zt][i] += (dt / 6.f) * (acc[zt][i] + k[zt][i]);

    t_cur = t_nxt;
    t_nxt = t_fut;
  }
}

// ============ kernel 2: decode in place, 1 wave per 16-row slab, NO barriers ============
__global__ __launch_bounds__(256, 1)
void node_dec(const float* __restrict__ l2hw, const float* __restrict__ l2hb,
              const float* __restrict__ h2ow, const float* __restrict__ h2ob,
              float* __restrict__ out) {
  __shared__ __align__(16) f16 xb[4][16 * 64];
  __shared__ __align__(16) f16 hb[4][16 * 128];

  const int tid  = threadIdx.x;
  const int lane = tid & 63;
  const int wv   = tid >> 6;
  const int grp  = lane >> 4;
  const int bcol = lane & 15;
  const int r0   = (blockIdx.x * 4 + wv) * 16;   // flattened [T*B] row base
  const f32x4 Z0 = {0.f, 0.f, 0.f, 0.f};

  f16x8 aL[8][2], aO[4][4];
  f32x4 bL[8], bO[4];
#pragma unroll
  for (int ot = 0; ot < 8; ++ot) {
    aL[ot][0] = load_afrag(l2hw, 64, ot, 0, lane);
    aL[ot][1] = load_afrag(l2hw, 64, ot, 1, lane);
    bL[ot] = *(const f32x4*)(l2hb + ot * 16 + grp * 4);
  }
#pragma unroll
  for (int t = 0; t < 4; ++t) {
#pragma unroll
    for (int kf = 0; kf < 4; ++kf) aO[t][kf] = load_afrag(h2ow, 128, t, kf, lane);
    bO[t] = *(const f32x4*)(h2ob + t * 16 + grp * 4);
  }

  // read this wave's 16x64 z slab (written by kernel 1), then overwrite it
  f32x4 zr[4];
#pragma unroll
  for (int ot = 0; ot < 4; ++ot) {
    zr[ot] = *(const f32x4*)(out + (size_t)(r0 + bcol) * LATENT + ot * 16 + grp * 4);
  }
#pragma unroll
  for (int ot = 0; ot < 4; ++ot) dwrite(xb[wv], 128, ot * 16 + grp * 4, zr[ot], lane);

  const f16x8 v0 = bfrag(xb[wv], 128, 0, lane);
  const f16x8 v1 = bfrag(xb[wv], 128, 32, lane);
#pragma unroll
  for (int ot = 0; ot < 8; ++ot) {
    f32x4 d = MFMA16(aL[ot][0], v0, bL[ot]);
    d = MFMA16(aL[ot][1], v1, d);
#pragma unroll
    for (int i = 0; i < 4; ++i) d[i] = fmaxf(d[i], 0.f);
    dwrite(hb[wv], 256, ot * 16 + grp * 4, d, lane);
  }
  f16x8 h[4];
#pragma unroll
  for (int kf = 0; kf < 4; ++kf) h[kf] = bfrag(hb[wv], 256, kf * 32, lane);
#pragma unroll
  for (int t = 0; t < 4; ++t) {
    f32x4 c0 = MFMA16(aO[t][0], h[0], bO[t]);
    c0 = MFMA16(aO[t][1], h[1], c0);
    f32x4 c1 = MFMA16(aO[t][2], h[2], Z0);
    c1 = MFMA16(aO[t][3], h[3], c1);
    f32x4 o = c0 + c1;
    *(f32x4*)(out + (size_t)(r0 + bcol) * LATENT + t * 16 + grp * 4) = o;
  }
}

extern "C" void kernel_launch(void* const* d_in, const int* in_sizes, int n_in,
                              void* d_out, int out_size, void* d_ws, size_t ws_size,
                              hipStream_t stream) {
  const float* z0   = (const float*)d_in[0];
  const float* tg   = (const float*)d_in[1];
  const float* fc1w = (const float*)d_in[2];
  const float* fc1b = (const float*)d_in[3];
  const float* fc2w = (const float*)d_in[4];
  const float* fc2b = (const float*)d_in[5];
  const float* fc3w = (const float*)d_in[6];
  const float* fc3b = (const float*)d_in[7];
  const float* l2hw = (const float*)d_in[8];
  const float* l2hb = (const float*)d_in[9];
  const float* h2ow = (const float*)d_in[10];
  const float* h2ob = (const float*)d_in[11];
  float* out = (float*)d_out;

  const int Btot = in_sizes[0] / LATENT;  // 4096
  const int T    = in_sizes[1];           // 100

  node_int<<<dim3(Btot / 16), dim3(64), 0, stream>>>(z0, tg, fc1w, fc1b, fc2w, fc2b,
                                                     fc3w, fc3b, out, Btot, T);
  const int slabs = (T * Btot) / 16;      // 25600
  node_dec<<<dim3(slabs / 4), dim3(256), 0, stream>>>(l2hw, l2hb, h2ow, h2ob, out);
}

// Round 5
// 390.164 us; speedup vs baseline: 2.5694x; 2.5694x over previous
//
#include <hip/hip_runtime.h>

typedef _Float16 f16;
typedef _Float16 f16x4 __attribute__((ext_vector_type(4)));
typedef _Float16 f16x8 __attribute__((ext_vector_type(8)));
typedef __fp16   h16x2 __attribute__((ext_vector_type(2)));
typedef float    f32x4 __attribute__((ext_vector_type(4)));

struct h16x2x2 { h16x2 lo, hi; };

#define MFMA16(a,b,c) __builtin_amdgcn_mfma_f32_16x16x32_f16((a),(b),(c),0,0,0)

#define LATENT 64
#define HIDDEN 128
#define ROWS   8   // valid batch rows per block (16-row MFMA tile, half-filled)

// Barrier that orders LDS only: waits this wave's ds ops, then s_barrier.
// No vmcnt drain -> global stores never block the barrier.
__device__ __forceinline__ void bar_lds() {
  asm volatile("s_waitcnt lgkmcnt(0)\n\ts_barrier" ::: "memory");
}

// A-fragment of W[out][K] for out-tile `tile`, k-chunk kf (32 wide).
// mfma_f32_16x16x32_f16 A layout: row = lane%16, k = kf*32 + 8*(lane/16)+j
__device__ __forceinline__ f16x8 load_afrag(const float* __restrict__ W, int K,
                                            int tile, int kf, int lane) {
  const int row = tile * 16 + (lane & 15);
  const int k0  = kf * 32 + (lane >> 4) * 8;
  const float* p = W + row * K + k0;
  f16x8 r;
#pragma unroll
  for (int j = 0; j < 8; ++j) r[j] = (f16)p[j];
  return r;
}

// B-fragment from LDS activation tile [16 rows][dims] f16, XOR-swizzled rows.
__device__ __forceinline__ f16x8 bfrag(const f16* buf, int rowb, int k0, int lane) {
  const int b  = lane & 15;
  const int kk = k0 + (lane >> 4) * 8;
  const int off = b * rowb + ((kk * 2) ^ ((b & 7) << 4));
  return *(const f16x8*)((const char*)buf + off);
}

// Write one D-tile (f32x4 -> f16x4, packed RTZ cvt) into an activation buffer.
__device__ __forceinline__ void dwrite(f16* buf, int rowb, int dbase, f32x4 v, int lane) {
  const int b = lane & 15;
  h16x2x2 p;
  p.lo = __builtin_amdgcn_cvt_pkrtz(v[0], v[1]);
  p.hi = __builtin_amdgcn_cvt_pkrtz(v[2], v[3]);
  const f16x4 h = __builtin_bit_cast(f16x4, p);
  const int off = b * rowb + ((dbase * 2) ^ ((b & 7) << 4));
  *(f16x4*)((char*)buf + off) = h;
}

__device__ __forceinline__ f32x4 elu4(f32x4 d) {
#pragma unroll
  for (int i = 0; i < 4; ++i) {
    const float e = __expf(d[i]) - 1.f;
    d[i] = d[i] > 0.f ? d[i] : e;
  }
  return d;
}

__global__ __launch_bounds__(256, 2)
void node_rk4_kernel(const float* __restrict__ z0,   const float* __restrict__ tg,
                     const float* __restrict__ fc1w, const float* __restrict__ fc1b,
                     const float* __restrict__ fc2w, const float* __restrict__ fc2b,
                     const float* __restrict__ fc3w, const float* __restrict__ fc3b,
                     const float* __restrict__ l2hw, const float* __restrict__ l2hb,
                     const float* __restrict__ h2ow, const float* __restrict__ h2ob,
                     float* __restrict__ out, int Btot, int T) {
  __shared__ __align__(16) f16 xbuf[16 * 64];    // f-input / z staging
  __shared__ __align__(16) f16 h1buf[16 * 128];  // hidden1 / decoder hidden
  __shared__ __align__(16) f16 h2buf[16 * 128];  // hidden2

  const int tid  = threadIdx.x;
  const int lane = tid & 63;
  const int wv   = tid >> 6;   // 0..3; owns hidden tiles {2wv,2wv+1}, latent tile wv
  const int grp  = lane >> 4;
  const int bcol = lane & 15;
  const int row0 = blockIdx.x * ROWS;
  const f32x4 Z0 = {0.f, 0.f, 0.f, 0.f};

  // ---- weights -> registers (per-wave slices; ~104 VGPR total) ----
  f16x8 a1[2][2], aL[2][2], a2[2][4], a3[4], aO[4];
  f32x4 b1[2], b2[2], bL[2], b3, bO;
#pragma unroll
  for (int ot = 0; ot < 2; ++ot) {
#pragma unroll
    for (int kf = 0; kf < 2; ++kf) {
      a1[ot][kf] = load_afrag(fc1w, 64, 2 * wv + ot, kf, lane);
      aL[ot][kf] = load_afrag(l2hw, 64, 2 * wv + ot, kf, lane);
    }
#pragma unroll
    for (int kf = 0; kf < 4; ++kf) a2[ot][kf] = load_afrag(fc2w, 128, 2 * wv + ot, kf, lane);
    const int d = (2 * wv + ot) * 16 + grp * 4;
    b1[ot] = *(const f32x4*)(fc1b + d);
    b2[ot] = *(const f32x4*)(fc2b + d);
    bL[ot] = *(const f32x4*)(l2hb + d);
  }
#pragma unroll
  for (int kf = 0; kf < 4; ++kf) {
    a3[kf] = load_afrag(fc3w, 128, wv, kf, lane);
    aO[kf] = load_afrag(h2ow, 128, wv, kf, lane);
  }
  const int dz = wv * 16 + grp * 4;
  b3 = *(const f32x4*)(fc3b + dz);
  bO = *(const f32x4*)(h2ob + dz);

  // ---- z state: lane holds z[row][dz..dz+3]; garbage lanes clamped ----
  const int rb = min(row0 + bcol, Btot - 1);
  f32x4 z = *(const f32x4*)(z0 + (size_t)rb * LATENT + dz);

  // f on staged xbuf: layer1 -> BAR -> layer2 -> BAR -> layer3 (returns k)
  auto feval = [&]() -> f32x4 {
    const f16x8 v0 = bfrag(xbuf, 128, 0, lane);
    const f16x8 v1 = bfrag(xbuf, 128, 32, lane);
#pragma unroll
    for (int ot = 0; ot < 2; ++ot) {
      f32x4 d = MFMA16(a1[ot][0], v0, b1[ot]);
      d = MFMA16(a1[ot][1], v1, d);
      d = elu4(d);
      dwrite(h1buf, 256, (2 * wv + ot) * 16 + grp * 4, d, lane);
    }
    bar_lds();
    f16x8 h[4];
#pragma unroll
    for (int kf = 0; kf < 4; ++kf) h[kf] = bfrag(h1buf, 256, kf * 32, lane);
#pragma unroll
    for (int ot = 0; ot < 2; ++ot) {
      f32x4 c0 = MFMA16(a2[ot][0], h[0], b2[ot]);
      c0 = MFMA16(a2[ot][1], h[1], c0);
      f32x4 c1 = MFMA16(a2[ot][2], h[2], Z0);
      c1 = MFMA16(a2[ot][3], h[3], c1);
      f32x4 d = elu4(c0 + c1);
      dwrite(h2buf, 256, (2 * wv + ot) * 16 + grp * 4, d, lane);
    }
    bar_lds();
    f16x8 g[4];
#pragma unroll
    for (int kf = 0; kf < 4; ++kf) g[kf] = bfrag(h2buf, 256, kf * 32, lane);
    f32x4 c0 = MFMA16(a3[0], g[0], b3);
    c0 = MFMA16(a3[1], g[1], c0);
    f32x4 c1 = MFMA16(a3[2], g[2], Z0);
    c1 = MFMA16(a3[3], g[3], c1);
    return c0 + c1;
  };

  float t_cur = tg[0];
  float t_nxt = tg[1];
  for (int s = 0;; ++s) {
    // ---- stage z (k1 input + decoder input) ----
    dwrite(xbuf, 128, dz, z, lane);
    bar_lds();                                   // BAR A: xbuf w->r

    // ---- inline decode of z_s: h2o(relu(l2h(z))) ----
    {
      const f16x8 x0 = bfrag(xbuf, 128, 0, lane);
      const f16x8 x1 = bfrag(xbuf, 128, 32, lane);
#pragma unroll
      for (int ot = 0; ot < 2; ++ot) {
        f32x4 d = MFMA16(aL[ot][0], x0, bL[ot]);
        d = MFMA16(aL[ot][1], x1, d);
#pragma unroll
        for (int i = 0; i < 4; ++i) d[i] = fmaxf(d[i], 0.f);
        dwrite(h1buf, 256, (2 * wv + ot) * 16 + grp * 4, d, lane);
      }
      bar_lds();                                 // BAR B: h1 w->r
      f16x8 h[4];
#pragma unroll
      for (int kf = 0; kf < 4; ++kf) h[kf] = bfrag(h1buf, 256, kf * 32, lane);
      bar_lds();                                 // BAR C: h1 r->w (reads landed via lgkm)
      f32x4 c0 = MFMA16(aO[0], h[0], bO);
      c0 = MFMA16(aO[1], h[1], c0);
      f32x4 c1 = MFMA16(aO[2], h[2], Z0);
      c1 = MFMA16(aO[3], h[3], c1);
      f32x4 o = c0 + c1;
      if (bcol < ROWS)  // direct store from accumulators; masked lanes drop
        *(f32x4*)(out + ((size_t)s * Btot + row0 + bcol) * LATENT + dz) = o;
    }
    if (s == T - 1) break;

    const float t_fut = tg[s + 2 < T ? s + 2 : T - 1];
    const float dt = t_nxt - t_cur;

    // ---- RK4 (xbuf holds z already) ----
    f32x4 k = feval();                           // k1
    f32x4 acc = k, xs;
#pragma unroll
    for (int i = 0; i < 4; ++i) xs[i] = z[i] + 0.5f * dt * k[i];
    dwrite(xbuf, 128, dz, xs, lane);
    bar_lds();
    k = feval();                                 // k2
#pragma unroll
    for (int i = 0; i < 4; ++i) { acc[i] += 2.f * k[i]; xs[i] = z[i] + 0.5f * dt * k[i]; }
    dwrite(xbuf, 128, dz, xs, lane);
    bar_lds();
    k = feval();                                 // k3
#pragma unroll
    for (int i = 0; i < 4; ++i) { acc[i] += 2.f * k[i]; xs[i] = z[i] + dt * k[i]; }
    dwrite(xbuf, 128, dz, xs, lane);
    bar_lds();
    k = feval();                                 // k4
#pragma unroll
    for (int i = 0; i < 4; ++i) z[i] += (dt / 6.f) * (acc[i] + k[i]);

    t_cur = t_nxt;
    t_nxt = t_fut;
  }
}

extern "C" void kernel_launch(void* const* d_in, const int* in_sizes, int n_in,
                              void* d_out, int out_size, void* d_ws, size_t ws_size,
                              hipStream_t stream) {
  const float* z0   = (const float*)d_in[0];
  const float* tg   = (const float*)d_in[1];
  const float* fc1w = (const float*)d_in[2];
  const float* fc1b = (const float*)d_in[3];
  const float* fc2w = (const float*)d_in[4];
  const float* fc2b = (const float*)d_in[5];
  const float* fc3w = (const float*)d_in[6];
  const float* fc3b = (const float*)d_in[7];
  const float* l2hw = (const float*)d_in[8];
  const float* l2hb = (const float*)d_in[9];
  const float* h2ow = (const float*)d_in[10];
  const float* h2ob = (const float*)d_in[11];
  float* out = (float*)d_out;

  const int Btot = in_sizes[0] / LATENT;  // 4096
  const int T    = in_sizes[1];           // 100

  dim3 grid((Btot + ROWS - 1) / ROWS), block(256);
  node_rk4_kernel<<<grid, block, 0, stream>>>(z0, tg, fc1w, fc1b, fc2w, fc2b,
                                              fc3w, fc3b, l2hw, l2hb, h2ow, h2ob,
                                              out, Btot, T);
}

// Round 6
// 300.056 us; speedup vs baseline: 3.3410x; 1.3003x over previous
//
#include <hip/hip_runtime.h>

typedef _Float16 f16;
typedef _Float16 f16x4 __attribute__((ext_vector_type(4)));
typedef _Float16 f16x8 __attribute__((ext_vector_type(8)));
typedef __fp16   h16x2 __attribute__((ext_vector_type(2)));
typedef float    f32x4 __attribute__((ext_vector_type(4)));

struct h16x2x2 { h16x2 lo, hi; };

#define MFMA16(a,b,c) __builtin_amdgcn_mfma_f32_16x16x32_f16((a),(b),(c),0,0,0)

#define LATENT 64
#define HIDDEN 128

// Barrier that orders LDS only: waits this wave's ds ops, then s_barrier.
// No vmcnt drain -> global stores never block the barrier.
__device__ __forceinline__ void bar_lds() {
  asm volatile("s_waitcnt lgkmcnt(0)\n\ts_barrier" ::: "memory");
}

// A-fragment of W[out][K] for out-tile `tile`, k-chunk kf (32 wide).
// mfma_f32_16x16x32_f16 A layout: row = lane%16, k = kf*32 + 8*(lane/16)+j
__device__ __forceinline__ f16x8 load_afrag(const float* __restrict__ W, int K,
                                            int tile, int kf, int lane) {
  const int row = tile * 16 + (lane & 15);
  const int k0  = kf * 32 + (lane >> 4) * 8;
  const float* p = W + row * K + k0;
  f16x8 r;
#pragma unroll
  for (int j = 0; j < 8; ++j) r[j] = (f16)p[j];
  return r;
}

// B-fragment from LDS activation tile [16 rows][dims] f16, XOR-swizzled rows.
__device__ __forceinline__ f16x8 bfrag(const f16* buf, int rowb, int k0, int lane) {
  const int b  = lane & 15;
  const int kk = k0 + (lane >> 4) * 8;
  const int off = b * rowb + ((kk * 2) ^ ((b & 7) << 4));
  return *(const f16x8*)((const char*)buf + off);
}

// Write one D-tile (f32x4 -> f16x4, packed RTZ cvt) into an activation buffer.
__device__ __forceinline__ void dwrite(f16* buf, int rowb, int dbase, f32x4 v, int lane) {
  const int b = lane & 15;
  h16x2x2 p;
  p.lo = __builtin_amdgcn_cvt_pkrtz(v[0], v[1]);
  p.hi = __builtin_amdgcn_cvt_pkrtz(v[2], v[3]);
  const f16x4 h = __builtin_bit_cast(f16x4, p);
  const int off = b * rowb + ((dbase * 2) ^ ((b & 7) << 4));
  *(f16x4*)((char*)buf + off) = h;
}

__device__ __forceinline__ f32x4 elu4(f32x4 d) {
#pragma unroll
  for (int i = 0; i < 4; ++i) {
    const float e = __expf(d[i]) - 1.f;
    d[i] = d[i] > 0.f ? d[i] : e;
  }
  return d;
}

__global__ __launch_bounds__(256, 2)
void node_rk4_kernel(const float* __restrict__ z0,   const float* __restrict__ tg,
                     const float* __restrict__ fc1w, const float* __restrict__ fc1b,
                     const float* __restrict__ fc2w, const float* __restrict__ fc2b,
                     const float* __restrict__ fc3w, const float* __restrict__ fc3b,
                     const float* __restrict__ l2hw, const float* __restrict__ l2hb,
                     const float* __restrict__ h2ow, const float* __restrict__ h2ob,
                     float* __restrict__ out, int Btot, int T) {
  __shared__ __align__(16) f16 xbuf[16 * 64];    // f-input / z staging
  __shared__ __align__(16) f16 h1buf[16 * 128];  // fc1 hidden
  __shared__ __align__(16) f16 h2buf[16 * 128];  // fc2 hidden
  __shared__ __align__(16) f16 dch1[16 * 128];   // decoder hidden (l2h)

  const int tid  = threadIdx.x;
  const int lane = tid & 63;
  const int wv   = tid >> 6;   // 0..3; owns hidden tiles {2wv,2wv+1}, latent tile wv
  const int grp  = lane >> 4;
  const int bcol = lane & 15;
  const int row0 = blockIdx.x * 16;
  const f32x4 Z0 = {0.f, 0.f, 0.f, 0.f};

  // ---- weights -> registers (per-wave slices) ----
  f16x8 a1[2][2], aL[2][2], a2[2][4], a3[4], aO[4];
  f32x4 b1[2], b2[2], bL[2], b3, bO;
#pragma unroll
  for (int ot = 0; ot < 2; ++ot) {
#pragma unroll
    for (int kf = 0; kf < 2; ++kf) {
      a1[ot][kf] = load_afrag(fc1w, 64, 2 * wv + ot, kf, lane);
      aL[ot][kf] = load_afrag(l2hw, 64, 2 * wv + ot, kf, lane);
    }
#pragma unroll
    for (int kf = 0; kf < 4; ++kf) a2[ot][kf] = load_afrag(fc2w, 128, 2 * wv + ot, kf, lane);
    const int d = (2 * wv + ot) * 16 + grp * 4;
    b1[ot] = *(const f32x4*)(fc1b + d);
    b2[ot] = *(const f32x4*)(fc2b + d);
    bL[ot] = *(const f32x4*)(l2hb + d);
  }
#pragma unroll
  for (int kf = 0; kf < 4; ++kf) {
    a3[kf] = load_afrag(fc3w, 128, wv, kf, lane);
    aO[kf] = load_afrag(h2ow, 128, wv, kf, lane);
  }
  const int dz = wv * 16 + grp * 4;
  b3 = *(const f32x4*)(fc3b + dz);
  bO = *(const f32x4*)(h2ob + dz);

  // ---- z state: lane holds z[row0+bcol][dz..dz+3] (D layout) ----
  f32x4 z = *(const f32x4*)(z0 + (size_t)(row0 + bcol) * LATENT + dz);

  // layer pieces (no internal barriers; caller places bar_lds between)
  auto l1 = [&]() {                       // xbuf -> h1buf (fc1+elu)
    const f16x8 v0 = bfrag(xbuf, 128, 0, lane);
    const f16x8 v1 = bfrag(xbuf, 128, 32, lane);
#pragma unroll
    for (int ot = 0; ot < 2; ++ot) {
      f32x4 d = MFMA16(a1[ot][0], v0, b1[ot]);
      d = MFMA16(a1[ot][1], v1, d);
      d = elu4(d);
      dwrite(h1buf, 256, (2 * wv + ot) * 16 + grp * 4, d, lane);
    }
  };
  auto l2 = [&]() {                       // h1buf -> h2buf (fc2+elu)
    f16x8 h[4];
#pragma unroll
    for (int kf = 0; kf < 4; ++kf) h[kf] = bfrag(h1buf, 256, kf * 32, lane);
#pragma unroll
    for (int ot = 0; ot < 2; ++ot) {
      f32x4 c0 = MFMA16(a2[ot][0], h[0], b2[ot]);
      c0 = MFMA16(a2[ot][1], h[1], c0);
      f32x4 c1 = MFMA16(a2[ot][2], h[2], Z0);
      c1 = MFMA16(a2[ot][3], h[3], c1);
      f32x4 d = elu4(c0 + c1);
      dwrite(h2buf, 256, (2 * wv + ot) * 16 + grp * 4, d, lane);
    }
  };
  auto l3 = [&]() -> f32x4 {              // h2buf -> k (fc3)
    f16x8 g[4];
#pragma unroll
    for (int kf = 0; kf < 4; ++kf) g[kf] = bfrag(h2buf, 256, kf * 32, lane);
    f32x4 c0 = MFMA16(a3[0], g[0], b3);
    c0 = MFMA16(a3[1], g[1], c0);
    f32x4 c1 = MFMA16(a3[2], g[2], Z0);
    c1 = MFMA16(a3[3], g[3], c1);
    return c0 + c1;
  };

  // prologue: stage z_0
  dwrite(xbuf, 128, dz, z, lane);
  bar_lds();

  float t_cur = tg[0];
  float t_nxt = tg[1];
  for (int s = 0;; ++s) {
    const bool last = (s == T - 1);

    // ---- seg B: dec-l1 (l2h+relu) + k1-l1 (fc1+elu), both read xbuf ----
    {
      const f16x8 x0 = bfrag(xbuf, 128, 0, lane);
      const f16x8 x1 = bfrag(xbuf, 128, 32, lane);
#pragma unroll
      for (int ot = 0; ot < 2; ++ot) {
        f32x4 d = MFMA16(aL[ot][0], x0, bL[ot]);
        d = MFMA16(aL[ot][1], x1, d);
#pragma unroll
        for (int i = 0; i < 4; ++i) d[i] = fmaxf(d[i], 0.f);
        dwrite(dch1, 256, (2 * wv + ot) * 16 + grp * 4, d, lane);
      }
      if (!last) {
#pragma unroll
        for (int ot = 0; ot < 2; ++ot) {
          f32x4 d = MFMA16(a1[ot][0], x0, b1[ot]);
          d = MFMA16(a1[ot][1], x1, d);
          d = elu4(d);
          dwrite(h1buf, 256, (2 * wv + ot) * 16 + grp * 4, d, lane);
        }
      }
    }
    bar_lds();

    // ---- seg C: dec-l2 (h2o) + global store + k1-l2 (fc2) ----
    {
      f16x8 hd[4];
#pragma unroll
      for (int kf = 0; kf < 4; ++kf) hd[kf] = bfrag(dch1, 256, kf * 32, lane);
      f32x4 c0 = MFMA16(aO[0], hd[0], bO);
      c0 = MFMA16(aO[1], hd[1], c0);
      f32x4 c1 = MFMA16(aO[2], hd[2], Z0);
      c1 = MFMA16(aO[3], hd[3], c1);
      f32x4 o = c0 + c1;
      *(f32x4*)(out + ((size_t)s * Btot + row0 + bcol) * LATENT + dz) = o;
      if (!last) l2();
    }
    if (last) break;
    bar_lds();

    const float t_fut = tg[s + 2 < T ? s + 2 : T - 1];
    const float dt = t_nxt - t_cur;

    // ---- seg D: k1-l3 + stage x(k2) ----
    f32x4 k = l3();
    f32x4 acc = k, xs;
#pragma unroll
    for (int i = 0; i < 4; ++i) xs[i] = z[i] + 0.5f * dt * k[i];
    dwrite(xbuf, 128, dz, xs, lane);
    bar_lds();

    // ---- k2 ----
    l1(); bar_lds();
    l2(); bar_lds();
    k = l3();
#pragma unroll
    for (int i = 0; i < 4; ++i) { acc[i] += 2.f * k[i]; xs[i] = z[i] + 0.5f * dt * k[i]; }
    dwrite(xbuf, 128, dz, xs, lane);
    bar_lds();

    // ---- k3 ----
    l1(); bar_lds();
    l2(); bar_lds();
    k = l3();
#pragma unroll
    for (int i = 0; i < 4; ++i) { acc[i] += 2.f * k[i]; xs[i] = z[i] + dt * k[i]; }
    dwrite(xbuf, 128, dz, xs, lane);
    bar_lds();

    // ---- k4 ----
    l1(); bar_lds();
    l2(); bar_lds();
    k = l3();                            // seg A: k4-l3 + z update + stage z
#pragma unroll
    for (int i = 0; i < 4; ++i) z[i] += (dt / 6.f) * (acc[i] + k[i]);
    dwrite(xbuf, 128, dz, z, lane);
    bar_lds();

    t_cur = t_nxt;
    t_nxt = t_fut;
  }
}

extern "C" void kernel_launch(void* const* d_in, const int* in_sizes, int n_in,
                              void* d_out, int out_size, void* d_ws, size_t ws_size,
                              hipStream_t stream) {
  const float* z0   = (const float*)d_in[0];
  const float* tg   = (const float*)d_in[1];
  const float* fc1w = (const float*)d_in[2];
  const float* fc1b = (const float*)d_in[3];
  const float* fc2w = (const float*)d_in[4];
  const float* fc2b = (const float*)d_in[5];
  const float* fc3w = (const float*)d_in[6];
  const float* fc3b = (const float*)d_in[7];
  const float* l2hw = (const float*)d_in[8];
  const float* l2hb = (const float*)d_in[9];
  const float* h2ow = (const float*)d_in[10];
  const float* h2ob = (const float*)d_in[11];
  float* out = (float*)d_out;

  const int Btot = in_sizes[0] / LATENT;  // 4096
  const int T    = in_sizes[1];           // 100

  dim3 grid(Btot / 16), block(256);
  node_rk4_kernel<<<grid, block, 0, stream>>>(z0, tg, fc1w, fc1b, fc2w, fc2b,
                                              fc3w, fc3b, l2hw, l2hb, h2ow, h2ob,
                                              out, Btot, T);
}